// Round 4
// baseline (890.000 us; speedup 1.0000x reference)
//
#include <hip/hip_runtime.h>
#include <math.h>

#define S_LEN   2048
#define NHEADS  12
#define HD      128
#define DMODEL  1536
#define NBATCH  2

typedef __bf16 bf16x8 __attribute__((ext_vector_type(8)));
typedef float  f32x4  __attribute__((ext_vector_type(4)));
typedef unsigned short u16x8 __attribute__((ext_vector_type(8)));

// ALiBi slopes for n=12 heads: pow2_slopes(8) + pow2_slopes(16)[0::2][:4]
__constant__ float c_slopes[NHEADS] = {
    0.5f, 0.25f, 0.125f, 0.0625f, 0.03125f, 0.015625f, 0.0078125f, 0.00390625f,
    0.70710678118654752f, 0.35355339059327379f,
    0.17677669529663689f, 0.08838834764831845f
};

__device__ __forceinline__ unsigned short f2bf(float x) {
    unsigned int u = __float_as_uint(x);
    u += 0x7FFFu + ((u >> 16) & 1u);   // RNE (no NaN inputs here)
    return (unsigned short)(u >> 16);
}
__device__ __forceinline__ float bf2f(unsigned short h) {
    return __uint_as_float(((unsigned int)h) << 16);
}
__device__ __forceinline__ void splitf(float v, unsigned short &h, unsigned short &l) {
    h = f2bf(v);
    l = f2bf(v - bf2f(h));
}
__device__ __forceinline__ f32x4 mfma16(bf16x8 a, bf16x8 b, f32x4 c) {
    return __builtin_amdgcn_mfma_f32_16x16x32_bf16(a, b, c, 0, 0, 0);
}

// ---------------------------------------------------------------------------
// RoPE tables [S][64] fp32 (matches jnp fp32 pipeline)
// ---------------------------------------------------------------------------
__global__ void rope_table_kernel(float* __restrict__ cosT, float* __restrict__ sinT) {
    const int s = blockIdx.x;
    const int i = threadIdx.x;                       // 0..63
    double inv = exp(-((double)i / 64.0) * 9.210340371976184);  // 10000^(-i/64)
    float argf = (float)s * (float)inv;
    double a = (double)argf;
    cosT[s * 64 + i] = (float)cos(a);
    sinT[s * 64 + i] = (float)sin(a);
}

// ---------------------------------------------------------------------------
// Elementwise fp32 -> bf16 hi/lo split (8 elems/thread, vectorized)
// ---------------------------------------------------------------------------
__global__ __launch_bounds__(256)
void conv_hl_kernel(const float* __restrict__ src,
                    unsigned short* __restrict__ dh,
                    unsigned short* __restrict__ dl, int n8)
{
    int idx = blockIdx.x * 256 + threadIdx.x;
    if (idx >= n8) return;
    const float4* s = (const float4*)src + (size_t)idx * 2;
    float4 a = s[0], b = s[1];
    u16x8 hv, lv;
    unsigned short th, tl;
    splitf(a.x, th, tl); hv[0] = th; lv[0] = tl;
    splitf(a.y, th, tl); hv[1] = th; lv[1] = tl;
    splitf(a.z, th, tl); hv[2] = th; lv[2] = tl;
    splitf(a.w, th, tl); hv[3] = th; lv[3] = tl;
    splitf(b.x, th, tl); hv[4] = th; lv[4] = tl;
    splitf(b.y, th, tl); hv[5] = th; lv[5] = tl;
    splitf(b.z, th, tl); hv[6] = th; lv[6] = tl;
    splitf(b.w, th, tl); hv[7] = th; lv[7] = tl;
    *(u16x8*)(dh + (size_t)idx * 8) = hv;
    *(u16x8*)(dl + (size_t)idx * 8) = lv;
}

// ---------------------------------------------------------------------------
// Tiled transpose: (BH, S, HD) -> (BH, HD, S) for hi and lo arrays.
// ---------------------------------------------------------------------------
__global__ __launch_bounds__(256, 4)
void transpose_vt_kernel(const unsigned short* __restrict__ inH,
                         const unsigned short* __restrict__ inL,
                         unsigned short* __restrict__ outH,
                         unsigned short* __restrict__ outL)
{
    __shared__ unsigned short Th[64 * 65], Tl[64 * 65];
    const int tid = threadIdx.x;
    const int sx = blockIdx.x * 64, dx = blockIdx.y * 64;
    const int bh = blockIdx.z;
    const size_t ibase = (size_t)bh * S_LEN * HD;
    const size_t obase = (size_t)bh * HD * S_LEN;

#pragma unroll
    for (int t = 0; t < 2; t++) {
        int srow = (tid >> 3) + 32 * t;
        int c8 = tid & 7;
        u16x8 vh = *(const u16x8*)(inH + ibase + (size_t)(sx + srow) * HD + dx + c8 * 8);
        u16x8 vl = *(const u16x8*)(inL + ibase + (size_t)(sx + srow) * HD + dx + c8 * 8);
#pragma unroll
        for (int j = 0; j < 8; j++) {
            Th[(c8 * 8 + j) * 65 + srow] = vh[j];
            Tl[(c8 * 8 + j) * 65 + srow] = vl[j];
        }
    }
    __syncthreads();
#pragma unroll
    for (int t = 0; t < 2; t++) {
        int drow = (tid >> 3) + 32 * t;
        int c8 = tid & 7;
        u16x8 vh, vl;
#pragma unroll
        for (int j = 0; j < 8; j++) {
            vh[j] = Th[drow * 65 + c8 * 8 + j];
            vl[j] = Tl[drow * 65 + c8 * 8 + j];
        }
        *(u16x8*)(outH + obase + (size_t)(dx + drow) * S_LEN + sx + c8 * 8) = vh;
        *(u16x8*)(outL + obase + (size_t)(dx + drow) * S_LEN + sx + c8 * 8) = vl;
    }
}

// ---------------------------------------------------------------------------
// Split-bf16 GEMM with pre-converted hi/lo operands.
// C[M][N] = A[MxK] @ B[NxK]^T + bias.
// mode 0: fp32 out (O-projection). mode 1: fused QKV epilogue (RoPE on Q,K),
//   n-range selects dest: [0,1536)=Q, [1536,3072)=K, [3072,4608)=V.
// ---------------------------------------------------------------------------
#define BM 128
#define BN 128
#define BK 32
#define LDT 40   // LDS row stride in elems (32 + 8 pad, conflict-free frag reads)

__global__ __launch_bounds__(256, 2)
void gemm_hl_kernel(const unsigned short* __restrict__ Agh, const unsigned short* __restrict__ Agl,
                    const unsigned short* __restrict__ Bgh, const unsigned short* __restrict__ Bgl,
                    int M, int N, int K,
                    float* __restrict__ outF, const float* __restrict__ bO,
                    unsigned short* __restrict__ Qh, unsigned short* __restrict__ Ql,
                    unsigned short* __restrict__ Kh, unsigned short* __restrict__ Kl,
                    unsigned short* __restrict__ Vh, unsigned short* __restrict__ Vl,
                    const float* __restrict__ bq, const float* __restrict__ bk,
                    const float* __restrict__ bv,
                    const float* __restrict__ cosT, const float* __restrict__ sinT,
                    int mode)
{
    __shared__ unsigned short Ah[BM * LDT], Al[BM * LDT];
    __shared__ unsigned short Bh[BN * LDT], Bl[BN * LDT];

    const int tid  = threadIdx.x;
    const int lane = tid & 63;
    const int wid  = tid >> 6;
    const int wm   = wid >> 1, wn = wid & 1;
    const int m0   = blockIdx.x * BM, n0 = blockIdx.y * BN;
    const int l15  = lane & 15, l4 = lane >> 4;
    const int kq   = l4 * 8;

    // staging: thread t covers row t>>1, k-chunk (t&1)*16 (16 elems each array)
    const int srow = tid >> 1, skc = (tid & 1) * 16;
    const size_t abase = (size_t)(m0 + srow) * K + skc;
    const size_t bbase = (size_t)(n0 + srow) * K + skc;

    f32x4 acc[4][4] = {};

    u16x8 pah0 = *(const u16x8*)(Agh + abase);
    u16x8 pah1 = *(const u16x8*)(Agh + abase + 8);
    u16x8 pal0 = *(const u16x8*)(Agl + abase);
    u16x8 pal1 = *(const u16x8*)(Agl + abase + 8);
    u16x8 pbh0 = *(const u16x8*)(Bgh + bbase);
    u16x8 pbh1 = *(const u16x8*)(Bgh + bbase + 8);
    u16x8 pbl0 = *(const u16x8*)(Bgl + bbase);
    u16x8 pbl1 = *(const u16x8*)(Bgl + bbase + 8);

    const int KT = K / BK;
    for (int kt = 0; kt < KT; ++kt) {
        __syncthreads();
        *(u16x8*)&Ah[srow * LDT + skc]     = pah0;
        *(u16x8*)&Ah[srow * LDT + skc + 8] = pah1;
        *(u16x8*)&Al[srow * LDT + skc]     = pal0;
        *(u16x8*)&Al[srow * LDT + skc + 8] = pal1;
        *(u16x8*)&Bh[srow * LDT + skc]     = pbh0;
        *(u16x8*)&Bh[srow * LDT + skc + 8] = pbh1;
        *(u16x8*)&Bl[srow * LDT + skc]     = pbl0;
        *(u16x8*)&Bl[srow * LDT + skc + 8] = pbl1;
        __syncthreads();

        if (kt + 1 < KT) {
            size_t ao = abase + (size_t)(kt + 1) * BK;
            size_t bo2 = bbase + (size_t)(kt + 1) * BK;
            pah0 = *(const u16x8*)(Agh + ao);
            pah1 = *(const u16x8*)(Agh + ao + 8);
            pal0 = *(const u16x8*)(Agl + ao);
            pal1 = *(const u16x8*)(Agl + ao + 8);
            pbh0 = *(const u16x8*)(Bgh + bo2);
            pbh1 = *(const u16x8*)(Bgh + bo2 + 8);
            pbl0 = *(const u16x8*)(Bgl + bo2);
            pbl1 = *(const u16x8*)(Bgl + bo2 + 8);
        }

        bf16x8 ah[4], al[4], bh[4], bl[4];
#pragma unroll
        for (int mi = 0; mi < 4; mi++) {
            int r = wm * 64 + mi * 16 + l15;
            ah[mi] = *(const bf16x8*)&Ah[r * LDT + kq];
            al[mi] = *(const bf16x8*)&Al[r * LDT + kq];
        }
#pragma unroll
        for (int ni = 0; ni < 4; ni++) {
            int r = wn * 64 + ni * 16 + l15;
            bh[ni] = *(const bf16x8*)&Bh[r * LDT + kq];
            bl[ni] = *(const bf16x8*)&Bl[r * LDT + kq];
        }
        __builtin_amdgcn_s_setprio(1);
#pragma unroll
        for (int mi = 0; mi < 4; mi++) {
#pragma unroll
            for (int ni = 0; ni < 4; ni++) {
                acc[mi][ni] = mfma16(ah[mi], bh[ni], acc[mi][ni]);
                acc[mi][ni] = mfma16(ah[mi], bl[ni], acc[mi][ni]);
                acc[mi][ni] = mfma16(al[mi], bh[ni], acc[mi][ni]);
            }
        }
        __builtin_amdgcn_s_setprio(0);
    }

    // epilogue
#pragma unroll
    for (int ni = 0; ni < 4; ni++) {
        int col = n0 + wn * 64 + ni * 16 + l15;
        float bvv;
        unsigned short *dh = nullptr, *dl = nullptr;
        int colL = col, dorope = 0;
        if (mode == 0) {
            bvv = bO[col];
        } else {
            int which = col / 1536;            // block-uniform (BN | 1536)
            colL = col - which * 1536;
            const float* bias = (which == 0) ? bq : (which == 1) ? bk : bv;
            dh = (which == 0) ? Qh : (which == 1) ? Kh : Vh;
            dl = (which == 0) ? Ql : (which == 1) ? Kl : Vl;
            dorope = (which < 2);
            bvv = bias[colL];
        }
        int hcol = colL >> 7;            // head
        int d    = colL & (HD - 1);      // dim within head
#pragma unroll
        for (int mi = 0; mi < 4; mi++) {
#pragma unroll
            for (int r = 0; r < 4; r++) {
                int row = m0 + wm * 64 + mi * 16 + l4 * 4 + r;
                float v = acc[mi][ni][r] + bvv;
                if (mode == 0) {
                    outF[(size_t)row * N + col] = v;
                } else {
                    int bb = row >> 11;
                    int ss = row & (S_LEN - 1);
                    if (dorope) {
                        float p  = __shfl_xor(v, 1);
                        float cc = cosT[ss * 64 + (d >> 1)];
                        float sn = sinT[ss * 64 + (d >> 1)];
                        v = (d & 1) ? fmaf(p, sn, v * cc) : fmaf(-p, sn, v * cc);
                    }
                    unsigned short hh, ll;
                    splitf(v, hh, ll);
                    size_t o = ((size_t)(bb * NHEADS + hcol) * S_LEN + ss) * HD + d;
                    dh[o] = hh;
                    dl[o] = ll;
                }
            }
        }
    }
}

// ---------------------------------------------------------------------------
// Flash attention, ALiBi (non-causal), split-bf16 MFMA.
// 2 waves/block x 32 q-rows each (2 fragments) = 64 q-rows/block; KB=32.
// Descending k-tile order (ALiBi bias grows with k) + exact skip-rescale.
// ---------------------------------------------------------------------------
#define KB  32
#define LKD 136   // K LDS stride (128 + 8 pad)
#define LVD 40    // V^T LDS stride (32 + 8 pad)
#define LPD 40    // P LDS stride (32 + 8 pad)

__global__ __launch_bounds__(128, 2)
void flash_kernel(const unsigned short* __restrict__ Qh, const unsigned short* __restrict__ Ql,
                  const unsigned short* __restrict__ Kh, const unsigned short* __restrict__ Kl,
                  const unsigned short* __restrict__ VTh, const unsigned short* __restrict__ VTl,
                  float* __restrict__ outF /* (B,S,D) */)
{
    __shared__ unsigned short Ksh[KB * LKD], Ksl[KB * LKD];
    __shared__ unsigned short Vth[HD * LVD], Vtl[HD * LVD];
    __shared__ unsigned short Psh[2 * 32 * LPD], Psl[2 * 32 * LPD];

    const int tid  = threadIdx.x, lane = tid & 63, wid = tid >> 6;  // wid 0/1
    const int l15  = lane & 15, l4 = lane >> 4;
    const int kq   = l4 * 8;
    const int qt   = blockIdx.x, bh = blockIdx.y;
    const int b    = bh / NHEADS, h = bh % NHEADS;
    const float slope = c_slopes[h];
    const float scale = 0.088388347648318447f;   // 1/sqrt(128)

    const size_t base  = (size_t)bh * S_LEN * HD;
    const size_t vbase = (size_t)bh * HD * S_LEN;

    // Q fragments: 2 per wave (rows qt*64 + wid*32 + f*16 + l15)
    bf16x8 qfh[2][4], qfl[2][4];
#pragma unroll
    for (int f = 0; f < 2; f++) {
        const int qrow = qt * 64 + wid * 32 + f * 16 + l15;
#pragma unroll
        for (int ks = 0; ks < 4; ks++) {
            size_t o = base + (size_t)qrow * HD + ks * 32 + kq;
            qfh[f][ks] = *(const bf16x8*)(Qh + o);
            qfl[f][ks] = *(const bf16x8*)(Ql + o);
        }
    }

    float m_r[2][4], l_r[2][4];
#pragma unroll
    for (int f = 0; f < 2; f++)
#pragma unroll
        for (int r = 0; r < 4; r++) { m_r[f][r] = -1e30f; l_r[f][r] = 0.0f; }
    f32x4 oacc[2][8] = {};

    unsigned short* Pmh = &Psh[wid * 32 * LPD];
    unsigned short* Pml = &Psl[wid * 32 * LPD];

    for (int it = 0; it < S_LEN / KB; ++it) {
        const int kt = (S_LEN / KB - 1) - it;   // descending k
        __syncthreads();
        // stage K [key][hd] (128 threads x 4 iters, 16B vector ops)
#pragma unroll
        for (int i = 0; i < 4; i++) {
            int u = tid + 128 * i;
            int row = u >> 4, c8 = u & 15;
            size_t g = base + (size_t)(kt * KB + row) * HD + c8 * 8;
            *(u16x8*)&Ksh[row * LKD + c8 * 8] = *(const u16x8*)(Kh + g);
            *(u16x8*)&Ksl[row * LKD + c8 * 8] = *(const u16x8*)(Kl + g);
        }
        // stage V^T [hd][key] from pre-transposed global
#pragma unroll
        for (int i = 0; i < 4; i++) {
            int u = tid + 128 * i;
            int row = u >> 2, c = u & 3;
            size_t g = vbase + (size_t)row * S_LEN + kt * KB + c * 8;
            *(u16x8*)&Vth[row * LVD + c * 8] = *(const u16x8*)(VTh + g);
            *(u16x8*)&Vtl[row * LVD + c * 8] = *(const u16x8*)(VTl + g);
        }
        __syncthreads();

        // QK^T: per fragment D[q16 x key32] over hd=128
        f32x4 sc[2][2] = {};
        __builtin_amdgcn_s_setprio(1);
#pragma unroll
        for (int ks = 0; ks < 4; ks++) {
#pragma unroll
            for (int nf = 0; nf < 2; nf++) {
                int krow = nf * 16 + l15;
                bf16x8 kh = *(const bf16x8*)&Ksh[krow * LKD + ks * 32 + kq];
                bf16x8 kl = *(const bf16x8*)&Ksl[krow * LKD + ks * 32 + kq];
#pragma unroll
                for (int f = 0; f < 2; f++) {
                    sc[f][nf] = mfma16(qfh[f][ks], kh, sc[f][nf]);
                    sc[f][nf] = mfma16(qfh[f][ks], kl, sc[f][nf]);
                    sc[f][nf] = mfma16(qfl[f][ks], kh, sc[f][nf]);
                }
            }
        }
        __builtin_amdgcn_s_setprio(0);

        // online softmax; exact skip-rescale (descending k => max set early)
        float mnew[2][4];
        int grow = 0;
        const float bias0 = slope * (float)(kt * KB + l15);
        const float bias1 = slope * (float)(kt * KB + 16 + l15);
#pragma unroll
        for (int f = 0; f < 2; f++) {
#pragma unroll
            for (int r = 0; r < 4; r++) {
                float s0 = fmaf(sc[f][0][r], scale, bias0);
                float s1 = fmaf(sc[f][1][r], scale, bias1);
                sc[f][0][r] = s0;
                sc[f][1][r] = s1;
                float mx = fmaxf(s0, s1);
                mx = fmaxf(mx, __shfl_xor(mx, 1));
                mx = fmaxf(mx, __shfl_xor(mx, 2));
                mx = fmaxf(mx, __shfl_xor(mx, 4));
                mx = fmaxf(mx, __shfl_xor(mx, 8));
                mnew[f][r] = fmaxf(m_r[f][r], mx);
                grow |= (mnew[f][r] > m_r[f][r]) ? 1 : 0;
            }
        }
        if (__any(grow)) {
#pragma unroll
            for (int f = 0; f < 2; f++) {
#pragma unroll
                for (int r = 0; r < 4; r++) {
                    float corr = __expf(m_r[f][r] - mnew[f][r]);
                    m_r[f][r] = mnew[f][r];
                    l_r[f][r] *= corr;
#pragma unroll
                    for (int nf = 0; nf < 8; nf++) oacc[f][nf][r] *= corr;
                }
            }
        }
#pragma unroll
        for (int f = 0; f < 2; f++) {
#pragma unroll
            for (int r = 0; r < 4; r++) {
                float p0 = __expf(sc[f][0][r] - m_r[f][r]);
                float p1 = __expf(sc[f][1][r] - m_r[f][r]);
                sc[f][0][r] = p0;
                sc[f][1][r] = p1;
                float rs = p0 + p1;
                rs += __shfl_xor(rs, 1);
                rs += __shfl_xor(rs, 2);
                rs += __shfl_xor(rs, 4);
                rs += __shfl_xor(rs, 8);
                l_r[f][r] += rs;
            }
        }

        // P -> LDS (hi/lo), C-layout -> A-operand layout
#pragma unroll
        for (int f = 0; f < 2; f++) {
#pragma unroll
            for (int nf = 0; nf < 2; nf++) {
#pragma unroll
                for (int r = 0; r < 4; r++) {
                    unsigned short hh, ll;
                    splitf(sc[f][nf][r], hh, ll);
                    int row = f * 16 + l4 * 4 + r, col = nf * 16 + l15;
                    Pmh[row * LPD + col] = hh;
                    Pml[row * LPD + col] = ll;
                }
            }
        }
        asm volatile("s_waitcnt lgkmcnt(0)" ::: "memory");
        __builtin_amdgcn_sched_barrier(0);

        // PV: O[q16 x hd128] += P @ V per fragment
        bf16x8 ph[2], pl[2];
#pragma unroll
        for (int f = 0; f < 2; f++) {
            ph[f] = *(const bf16x8*)&Pmh[(f * 16 + l15) * LPD + kq];
            pl[f] = *(const bf16x8*)&Pml[(f * 16 + l15) * LPD + kq];
        }
        __builtin_amdgcn_s_setprio(1);
#pragma unroll
        for (int nf = 0; nf < 8; nf++) {
            int vrow = nf * 16 + l15;
            bf16x8 vh = *(const bf16x8*)&Vth[vrow * LVD + kq];
            bf16x8 vl = *(const bf16x8*)&Vtl[vrow * LVD + kq];
#pragma unroll
            for (int f = 0; f < 2; f++) {
                oacc[f][nf] = mfma16(ph[f], vh, oacc[f][nf]);
                oacc[f][nf] = mfma16(ph[f], vl, oacc[f][nf]);
                oacc[f][nf] = mfma16(pl[f], vh, oacc[f][nf]);
            }
        }
        __builtin_amdgcn_s_setprio(0);
    }

    // epilogue
#pragma unroll
    for (int f = 0; f < 2; f++) {
#pragma unroll
        for (int r = 0; r < 4; r++) {
            float inv = 1.0f / l_r[f][r];
            int srow = qt * 64 + wid * 32 + f * 16 + l4 * 4 + r;
            size_t ob = ((size_t)b * S_LEN + srow) * DMODEL + h * HD;
#pragma unroll
            for (int nf = 0; nf < 8; nf++) {
                outF[ob + nf * 16 + l15] = oacc[f][nf][r] * inv;
            }
        }
    }
}

// ---------------------------------------------------------------------------
extern "C" void kernel_launch(void* const* d_in, const int* in_sizes, int n_in,
                              void* d_out, int out_size, void* d_ws, size_t ws_size,
                              hipStream_t stream)
{
    const float* x  = (const float*)d_in[0];
    const float* Wq = (const float*)d_in[1];
    const float* bq = (const float*)d_in[2];
    const float* Wk = (const float*)d_in[3];
    const float* bk = (const float*)d_in[4];
    const float* Wv = (const float*)d_in[5];
    const float* bv = (const float*)d_in[6];
    const float* Wo = (const float*)d_in[7];
    const float* bo = (const float*)d_in[8];
    float* out = (float*)d_out;

    char* ws = (char*)d_ws;
    const size_t SZ = 12582912;                 // 6.29M elems * 2B

    float* cosT = (float*)ws;           ws += 524288;
    float* sinT = (float*)ws;           ws += 524288;
    unsigned short* Xh  = (unsigned short*)ws; ws += SZ;   // alias: AOh
    unsigned short* Xl  = (unsigned short*)ws; ws += SZ;   // alias: AOl
    unsigned short* Wch = (unsigned short*)ws; ws += 14155776;  // 4608x1536; alias: Woh
    unsigned short* Wcl = (unsigned short*)ws; ws += 14155776;  // alias: Wol
    unsigned short* Qhp = (unsigned short*)ws; ws += SZ;
    unsigned short* Qlp = (unsigned short*)ws; ws += SZ;
    unsigned short* Khp = (unsigned short*)ws; ws += SZ;
    unsigned short* Klp = (unsigned short*)ws; ws += SZ;
    unsigned short* Vhp = (unsigned short*)ws; ws += SZ;   // alias: attnO (fp32, spans Vhp+Vlp)
    unsigned short* Vlp = (unsigned short*)ws; ws += SZ;
    unsigned short* VTh = (unsigned short*)ws; ws += SZ;
    unsigned short* VTl = (unsigned short*)ws; ws += SZ;

    float* attnO = (float*)Vhp;                 // 25.2 MB, V dead after transpose
    unsigned short* AOh = Xh;                   // X dead after QKV GEMM
    unsigned short* AOl = Xl;
    unsigned short* Woh = Wch;                  // Wqkv dead after QKV GEMM
    unsigned short* Wol = Wcl;

    const int M = NBATCH * S_LEN;               // 4096
    const int NW = 1536 * 1536;                 // one weight matrix

    rope_table_kernel<<<dim3(S_LEN), dim3(64), 0, stream>>>(cosT, sinT);

    // convert x and the three QKV weights (concatenated along N)
    conv_hl_kernel<<<dim3(M * DMODEL / 8 / 256), 256, 0, stream>>>(x, Xh, Xl, M * DMODEL / 8);
    conv_hl_kernel<<<dim3(NW / 8 / 256), 256, 0, stream>>>(Wq, Wch, Wcl, NW / 8);
    conv_hl_kernel<<<dim3(NW / 8 / 256), 256, 0, stream>>>(Wk, Wch + (size_t)NW, Wcl + (size_t)NW, NW / 8);
    conv_hl_kernel<<<dim3(NW / 8 / 256), 256, 0, stream>>>(Wv, Wch + (size_t)2 * NW, Wcl + (size_t)2 * NW, NW / 8);

    // fused QKV projection: M=4096, N=4608, K=1536
    gemm_hl_kernel<<<dim3(M / BM, 4608 / BN), 256, 0, stream>>>(
        Xh, Xl, Wch, Wcl, M, 4608, DMODEL,
        nullptr, nullptr, Qhp, Qlp, Khp, Klp, Vhp, Vlp,
        bq, bk, bv, cosT, sinT, 1);

    transpose_vt_kernel<<<dim3(S_LEN / 64, HD / 64, NBATCH * NHEADS), 256, 0, stream>>>(
        Vhp, Vlp, VTh, VTl);

    conv_hl_kernel<<<dim3(NW / 8 / 256), 256, 0, stream>>>(Wo, Woh, Wol, NW / 8);

    flash_kernel<<<dim3(S_LEN / 64, NBATCH * NHEADS), 128, 0, stream>>>(
        Qhp, Qlp, Khp, Klp, VTh, VTl, attnO);

    conv_hl_kernel<<<dim3(M * DMODEL / 8 / 256), 256, 0, stream>>>(attnO, AOh, AOl, M * DMODEL / 8);

    // output projection
    gemm_hl_kernel<<<dim3(M / BM, DMODEL / BN), 256, 0, stream>>>(
        AOh, AOl, Woh, Wol, M, DMODEL, DMODEL,
        out, bo, nullptr, nullptr, nullptr, nullptr, nullptr, nullptr,
        nullptr, nullptr, nullptr, nullptr, nullptr, 0);
}

// Round 5
// 678.111 us; speedup vs baseline: 1.3125x; 1.3125x over previous
//
#include <hip/hip_runtime.h>
#include <math.h>

#define S_LEN   2048
#define NHEADS  12
#define HD      128
#define DMODEL  1536
#define NBATCH  2

typedef __bf16 bf16x8 __attribute__((ext_vector_type(8)));
typedef float  f32x4  __attribute__((ext_vector_type(4)));
typedef unsigned short u16x8 __attribute__((ext_vector_type(8)));

// ALiBi slopes for n=12 heads: pow2_slopes(8) + pow2_slopes(16)[0::2][:4]
__constant__ float c_slopes[NHEADS] = {
    0.5f, 0.25f, 0.125f, 0.0625f, 0.03125f, 0.015625f, 0.0078125f, 0.00390625f,
    0.70710678118654752f, 0.35355339059327379f,
    0.17677669529663689f, 0.08838834764831845f
};

__device__ __forceinline__ unsigned short f2bf(float x) {
    unsigned int u = __float_as_uint(x);
    u += 0x7FFFu + ((u >> 16) & 1u);   // RNE (no NaN inputs here)
    return (unsigned short)(u >> 16);
}
__device__ __forceinline__ float bf2f(unsigned short h) {
    return __uint_as_float(((unsigned int)h) << 16);
}
__device__ __forceinline__ void splitf(float v, unsigned short &h, unsigned short &l) {
    h = f2bf(v);
    l = f2bf(v - bf2f(h));
}
__device__ __forceinline__ f32x4 mfma16(bf16x8 a, bf16x8 b, f32x4 c) {
    return __builtin_amdgcn_mfma_f32_16x16x32_bf16(a, b, c, 0, 0, 0);
}

// ---------------------------------------------------------------------------
// RoPE tables [S][64] fp32 (matches jnp fp32 pipeline)
// ---------------------------------------------------------------------------
__global__ void rope_table_kernel(float* __restrict__ cosT, float* __restrict__ sinT) {
    const int s = blockIdx.x;
    const int i = threadIdx.x;                       // 0..63
    double inv = exp(-((double)i / 64.0) * 9.210340371976184);  // 10000^(-i/64)
    float argf = (float)s * (float)inv;
    double a = (double)argf;
    cosT[s * 64 + i] = (float)cos(a);
    sinT[s * 64 + i] = (float)sin(a);
}

// ---------------------------------------------------------------------------
// Elementwise fp32 -> bf16 hi/lo split (8 elems/thread, vectorized)
// ---------------------------------------------------------------------------
__global__ __launch_bounds__(256)
void conv_hl_kernel(const float* __restrict__ src,
                    unsigned short* __restrict__ dh,
                    unsigned short* __restrict__ dl, int n8)
{
    int idx = blockIdx.x * 256 + threadIdx.x;
    if (idx >= n8) return;
    const float4* s = (const float4*)src + (size_t)idx * 2;
    float4 a = s[0], b = s[1];
    u16x8 hv, lv;
    unsigned short th, tl;
    splitf(a.x, th, tl); hv[0] = th; lv[0] = tl;
    splitf(a.y, th, tl); hv[1] = th; lv[1] = tl;
    splitf(a.z, th, tl); hv[2] = th; lv[2] = tl;
    splitf(a.w, th, tl); hv[3] = th; lv[3] = tl;
    splitf(b.x, th, tl); hv[4] = th; lv[4] = tl;
    splitf(b.y, th, tl); hv[5] = th; lv[5] = tl;
    splitf(b.z, th, tl); hv[6] = th; lv[6] = tl;
    splitf(b.w, th, tl); hv[7] = th; lv[7] = tl;
    *(u16x8*)(dh + (size_t)idx * 8) = hv;
    *(u16x8*)(dl + (size_t)idx * 8) = lv;
}

// ---------------------------------------------------------------------------
// Tiled transpose: (BH, S, HD) -> (BH, HD, S) for hi and lo arrays.
// ---------------------------------------------------------------------------
__global__ __launch_bounds__(256, 4)
void transpose_vt_kernel(const unsigned short* __restrict__ inH,
                         const unsigned short* __restrict__ inL,
                         unsigned short* __restrict__ outH,
                         unsigned short* __restrict__ outL)
{
    __shared__ unsigned short Th[64 * 65], Tl[64 * 65];
    const int tid = threadIdx.x;
    const int sx = blockIdx.x * 64, dx = blockIdx.y * 64;
    const int bh = blockIdx.z;
    const size_t ibase = (size_t)bh * S_LEN * HD;
    const size_t obase = (size_t)bh * HD * S_LEN;

#pragma unroll
    for (int t = 0; t < 2; t++) {
        int srow = (tid >> 3) + 32 * t;
        int c8 = tid & 7;
        u16x8 vh = *(const u16x8*)(inH + ibase + (size_t)(sx + srow) * HD + dx + c8 * 8);
        u16x8 vl = *(const u16x8*)(inL + ibase + (size_t)(sx + srow) * HD + dx + c8 * 8);
#pragma unroll
        for (int j = 0; j < 8; j++) {
            Th[(c8 * 8 + j) * 65 + srow] = vh[j];
            Tl[(c8 * 8 + j) * 65 + srow] = vl[j];
        }
    }
    __syncthreads();
#pragma unroll
    for (int t = 0; t < 2; t++) {
        int drow = (tid >> 3) + 32 * t;
        int c8 = tid & 7;
        u16x8 vh, vl;
#pragma unroll
        for (int j = 0; j < 8; j++) {
            vh[j] = Th[drow * 65 + c8 * 8 + j];
            vl[j] = Tl[drow * 65 + c8 * 8 + j];
        }
        *(u16x8*)(outH + obase + (size_t)(dx + drow) * S_LEN + sx + c8 * 8) = vh;
        *(u16x8*)(outL + obase + (size_t)(dx + drow) * S_LEN + sx + c8 * 8) = vl;
    }
}

// ---------------------------------------------------------------------------
// Split-bf16 GEMM with pre-converted hi/lo operands.
// C[M][N] = A[MxK] @ B[NxK]^T + bias.
// mode 0: fp32 out (O-projection). mode 1: fused QKV epilogue (RoPE on Q,K),
//   n-range selects dest: [0,1536)=Q, [1536,3072)=K, [3072,4608)=V.
// ---------------------------------------------------------------------------
#define BM 128
#define BN 128
#define BK 32
#define LDT 40   // LDS row stride in elems (32 + 8 pad, conflict-free frag reads)

__global__ __launch_bounds__(256, 2)
void gemm_hl_kernel(const unsigned short* __restrict__ Agh, const unsigned short* __restrict__ Agl,
                    const unsigned short* __restrict__ Bgh, const unsigned short* __restrict__ Bgl,
                    int M, int N, int K,
                    float* __restrict__ outF, const float* __restrict__ bO,
                    unsigned short* __restrict__ Qh, unsigned short* __restrict__ Ql,
                    unsigned short* __restrict__ Kh, unsigned short* __restrict__ Kl,
                    unsigned short* __restrict__ Vh, unsigned short* __restrict__ Vl,
                    const float* __restrict__ bq, const float* __restrict__ bk,
                    const float* __restrict__ bv,
                    const float* __restrict__ cosT, const float* __restrict__ sinT,
                    int mode)
{
    __shared__ unsigned short Ah[BM * LDT], Al[BM * LDT];
    __shared__ unsigned short Bh[BN * LDT], Bl[BN * LDT];

    const int tid  = threadIdx.x;
    const int lane = tid & 63;
    const int wid  = tid >> 6;
    const int wm   = wid >> 1, wn = wid & 1;
    const int m0   = blockIdx.x * BM, n0 = blockIdx.y * BN;
    const int l15  = lane & 15, l4 = lane >> 4;
    const int kq   = l4 * 8;

    // staging: thread t covers row t>>1, k-chunk (t&1)*16 (16 elems each array)
    const int srow = tid >> 1, skc = (tid & 1) * 16;
    const size_t abase = (size_t)(m0 + srow) * K + skc;
    const size_t bbase = (size_t)(n0 + srow) * K + skc;

    f32x4 acc[4][4] = {};

    u16x8 pah0 = *(const u16x8*)(Agh + abase);
    u16x8 pah1 = *(const u16x8*)(Agh + abase + 8);
    u16x8 pal0 = *(const u16x8*)(Agl + abase);
    u16x8 pal1 = *(const u16x8*)(Agl + abase + 8);
    u16x8 pbh0 = *(const u16x8*)(Bgh + bbase);
    u16x8 pbh1 = *(const u16x8*)(Bgh + bbase + 8);
    u16x8 pbl0 = *(const u16x8*)(Bgl + bbase);
    u16x8 pbl1 = *(const u16x8*)(Bgl + bbase + 8);

    const int KT = K / BK;
    for (int kt = 0; kt < KT; ++kt) {
        __syncthreads();
        *(u16x8*)&Ah[srow * LDT + skc]     = pah0;
        *(u16x8*)&Ah[srow * LDT + skc + 8] = pah1;
        *(u16x8*)&Al[srow * LDT + skc]     = pal0;
        *(u16x8*)&Al[srow * LDT + skc + 8] = pal1;
        *(u16x8*)&Bh[srow * LDT + skc]     = pbh0;
        *(u16x8*)&Bh[srow * LDT + skc + 8] = pbh1;
        *(u16x8*)&Bl[srow * LDT + skc]     = pbl0;
        *(u16x8*)&Bl[srow * LDT + skc + 8] = pbl1;
        __syncthreads();

        if (kt + 1 < KT) {
            size_t ao = abase + (size_t)(kt + 1) * BK;
            size_t bo2 = bbase + (size_t)(kt + 1) * BK;
            pah0 = *(const u16x8*)(Agh + ao);
            pah1 = *(const u16x8*)(Agh + ao + 8);
            pal0 = *(const u16x8*)(Agl + ao);
            pal1 = *(const u16x8*)(Agl + ao + 8);
            pbh0 = *(const u16x8*)(Bgh + bo2);
            pbh1 = *(const u16x8*)(Bgh + bo2 + 8);
            pbl0 = *(const u16x8*)(Bgl + bo2);
            pbl1 = *(const u16x8*)(Bgl + bo2 + 8);
        }

        bf16x8 ah[4], al[4], bh[4], bl[4];
#pragma unroll
        for (int mi = 0; mi < 4; mi++) {
            int r = wm * 64 + mi * 16 + l15;
            ah[mi] = *(const bf16x8*)&Ah[r * LDT + kq];
            al[mi] = *(const bf16x8*)&Al[r * LDT + kq];
        }
#pragma unroll
        for (int ni = 0; ni < 4; ni++) {
            int r = wn * 64 + ni * 16 + l15;
            bh[ni] = *(const bf16x8*)&Bh[r * LDT + kq];
            bl[ni] = *(const bf16x8*)&Bl[r * LDT + kq];
        }
        __builtin_amdgcn_s_setprio(1);
#pragma unroll
        for (int mi = 0; mi < 4; mi++) {
#pragma unroll
            for (int ni = 0; ni < 4; ni++) {
                acc[mi][ni] = mfma16(ah[mi], bh[ni], acc[mi][ni]);
                acc[mi][ni] = mfma16(ah[mi], bl[ni], acc[mi][ni]);
                acc[mi][ni] = mfma16(al[mi], bh[ni], acc[mi][ni]);
            }
        }
        __builtin_amdgcn_s_setprio(0);
    }

    // epilogue
#pragma unroll
    for (int ni = 0; ni < 4; ni++) {
        int col = n0 + wn * 64 + ni * 16 + l15;
        float bvv;
        unsigned short *dh = nullptr, *dl = nullptr;
        int colL = col, dorope = 0;
        if (mode == 0) {
            bvv = bO[col];
        } else {
            int which = col / 1536;            // block-uniform (BN | 1536)
            colL = col - which * 1536;
            const float* bias = (which == 0) ? bq : (which == 1) ? bk : bv;
            dh = (which == 0) ? Qh : (which == 1) ? Kh : Vh;
            dl = (which == 0) ? Ql : (which == 1) ? Kl : Vl;
            dorope = (which < 2);
            bvv = bias[colL];
        }
        int hcol = colL >> 7;            // head
        int d    = colL & (HD - 1);      // dim within head
#pragma unroll
        for (int mi = 0; mi < 4; mi++) {
#pragma unroll
            for (int r = 0; r < 4; r++) {
                int row = m0 + wm * 64 + mi * 16 + l4 * 4 + r;
                float v = acc[mi][ni][r] + bvv;
                if (mode == 0) {
                    outF[(size_t)row * N + col] = v;
                } else {
                    int bb = row >> 11;
                    int ss = row & (S_LEN - 1);
                    if (dorope) {
                        float p  = __shfl_xor(v, 1);
                        float cc = cosT[ss * 64 + (d >> 1)];
                        float sn = sinT[ss * 64 + (d >> 1)];
                        v = (d & 1) ? fmaf(p, sn, v * cc) : fmaf(-p, sn, v * cc);
                    }
                    unsigned short hh, ll;
                    splitf(v, hh, ll);
                    size_t o = ((size_t)(bb * NHEADS + hcol) * S_LEN + ss) * HD + d;
                    dh[o] = hh;
                    dl[o] = ll;
                }
            }
        }
    }
}

// ---------------------------------------------------------------------------
// Flash attention, ALiBi (non-causal), split-bf16 MFMA.
// 4 waves x 16 q-rows = 64 q-rows/block (round-2 proven occupancy shape);
// descending k-tiles + exact vote-gated skip-rescale; fused hi/lo epilogue.
// ---------------------------------------------------------------------------
#define QB  64
#define KB  32
#define LKD 136   // K LDS stride (128 + 8 pad)
#define LVD 40    // V^T LDS stride (32 + 8 pad)
#define LPD 40    // P LDS stride (32 + 8 pad)

__global__ __launch_bounds__(256, 3)
void flash_kernel(const unsigned short* __restrict__ Qh, const unsigned short* __restrict__ Ql,
                  const unsigned short* __restrict__ Kh, const unsigned short* __restrict__ Kl,
                  const unsigned short* __restrict__ VTh, const unsigned short* __restrict__ VTl,
                  unsigned short* __restrict__ AOh, unsigned short* __restrict__ AOl)
{
    __shared__ unsigned short Ksh[KB * LKD], Ksl[KB * LKD];
    __shared__ unsigned short Vth[HD * LVD], Vtl[HD * LVD];
    __shared__ unsigned short Psh[4 * 16 * LPD], Psl[4 * 16 * LPD];

    const int tid  = threadIdx.x, lane = tid & 63, wid = tid >> 6;  // wid 0..3
    const int l15  = lane & 15, l4 = lane >> 4;
    const int kq   = l4 * 8;
    const int qt   = blockIdx.x, bh = blockIdx.y;
    const int b    = bh / NHEADS, h = bh % NHEADS;
    const float slope = c_slopes[h];
    const float scale = 0.088388347648318447f;   // 1/sqrt(128)

    const size_t base  = (size_t)bh * S_LEN * HD;
    const size_t vbase = (size_t)bh * HD * S_LEN;

    // Q fragments in registers (A-operand layout: m=l15, k-chunk by l4)
    bf16x8 qfh[4], qfl[4];
    {
        const int qrow = qt * QB + wid * 16 + l15;
#pragma unroll
        for (int ks = 0; ks < 4; ks++) {
            size_t o = base + (size_t)qrow * HD + ks * 32 + kq;
            qfh[ks] = *(const bf16x8*)(Qh + o);
            qfl[ks] = *(const bf16x8*)(Ql + o);
        }
    }

    float m_r[4], l_r[4];
#pragma unroll
    for (int r = 0; r < 4; r++) { m_r[r] = -1e30f; l_r[r] = 0.0f; }
    f32x4 oacc[8] = {};

    unsigned short* Pmh = &Psh[wid * 16 * LPD];
    unsigned short* Pml = &Psl[wid * 16 * LPD];

    for (int it = 0; it < S_LEN / KB; ++it) {
        const int kt = (S_LEN / KB - 1) - it;   // descending k (ALiBi max first)
        __syncthreads();
        // stage K [key][hd]: 16B vector ops only
#pragma unroll
        for (int i = 0; i < 2; i++) {
            int u = tid + 256 * i;
            int row = u >> 4, c8 = u & 15;
            size_t g = base + (size_t)(kt * KB + row) * HD + c8 * 8;
            *(u16x8*)&Ksh[row * LKD + c8 * 8] = *(const u16x8*)(Kh + g);
            *(u16x8*)&Ksl[row * LKD + c8 * 8] = *(const u16x8*)(Kl + g);
        }
        // stage V^T [hd][key] from pre-transposed global
#pragma unroll
        for (int i = 0; i < 2; i++) {
            int u = tid + 256 * i;
            int row = (u >> 2) & 127;
            int c = u & 3;
            size_t g = vbase + (size_t)row * S_LEN + kt * KB + c * 8;
            *(u16x8*)&Vth[row * LVD + c * 8] = *(const u16x8*)(VTh + g);
            *(u16x8*)&Vtl[row * LVD + c * 8] = *(const u16x8*)(VTl + g);
        }
        __syncthreads();

        // QK^T: D[q16 x key32] over hd=128
        f32x4 sc[2] = {};
        __builtin_amdgcn_s_setprio(1);
#pragma unroll
        for (int ks = 0; ks < 4; ks++) {
#pragma unroll
            for (int nf = 0; nf < 2; nf++) {
                int krow = nf * 16 + l15;
                bf16x8 kh = *(const bf16x8*)&Ksh[krow * LKD + ks * 32 + kq];
                bf16x8 kl = *(const bf16x8*)&Ksl[krow * LKD + ks * 32 + kq];
                sc[nf] = mfma16(qfh[ks], kh, sc[nf]);
                sc[nf] = mfma16(qfh[ks], kl, sc[nf]);
                sc[nf] = mfma16(qfl[ks], kh, sc[nf]);
            }
        }
        __builtin_amdgcn_s_setprio(0);

        // online softmax, exact skip-rescale (descending k: max locks in early)
        float mnew[4];
        int grow = 0;
        const float bias0 = slope * (float)(kt * KB + l15);
        const float bias1 = slope * (float)(kt * KB + 16 + l15);
#pragma unroll
        for (int r = 0; r < 4; r++) {
            float s0 = fmaf(sc[0][r], scale, bias0);
            float s1 = fmaf(sc[1][r], scale, bias1);
            sc[0][r] = s0;
            sc[1][r] = s1;
            float mx = fmaxf(s0, s1);
            mx = fmaxf(mx, __shfl_xor(mx, 1));
            mx = fmaxf(mx, __shfl_xor(mx, 2));
            mx = fmaxf(mx, __shfl_xor(mx, 4));
            mx = fmaxf(mx, __shfl_xor(mx, 8));
            mnew[r] = fmaxf(m_r[r], mx);
            grow |= (mnew[r] > m_r[r]) ? 1 : 0;
        }
        if (__any(grow)) {
#pragma unroll
            for (int r = 0; r < 4; r++) {
                float corr = __expf(m_r[r] - mnew[r]);
                m_r[r] = mnew[r];
                l_r[r] *= corr;
#pragma unroll
                for (int nf = 0; nf < 8; nf++) oacc[nf][r] *= corr;
            }
        }
#pragma unroll
        for (int r = 0; r < 4; r++) {
            float p0 = __expf(sc[0][r] - m_r[r]);
            float p1 = __expf(sc[1][r] - m_r[r]);
            sc[0][r] = p0;
            sc[1][r] = p1;
            float rs = p0 + p1;
            rs += __shfl_xor(rs, 1);
            rs += __shfl_xor(rs, 2);
            rs += __shfl_xor(rs, 4);
            rs += __shfl_xor(rs, 8);
            l_r[r] += rs;
        }

        // P -> LDS (hi/lo), C-layout -> A-operand layout
#pragma unroll
        for (int nf = 0; nf < 2; nf++) {
#pragma unroll
            for (int r = 0; r < 4; r++) {
                unsigned short hh, ll;
                splitf(sc[nf][r], hh, ll);
                int row = l4 * 4 + r, col = nf * 16 + l15;
                Pmh[row * LPD + col] = hh;
                Pml[row * LPD + col] = ll;
            }
        }
        asm volatile("s_waitcnt lgkmcnt(0)" ::: "memory");
        __builtin_amdgcn_sched_barrier(0);

        // PV: O[q16 x hd128] += P[q16 x key32] @ V[key32 x hd]
        bf16x8 ph = *(const bf16x8*)&Pmh[l15 * LPD + kq];
        bf16x8 pl = *(const bf16x8*)&Pml[l15 * LPD + kq];
        __builtin_amdgcn_s_setprio(1);
#pragma unroll
        for (int nf = 0; nf < 8; nf++) {
            int vrow = nf * 16 + l15;
            bf16x8 vh = *(const bf16x8*)&Vth[vrow * LVD + kq];
            bf16x8 vl = *(const bf16x8*)&Vtl[vrow * LVD + kq];
            oacc[nf] = mfma16(ph, vh, oacc[nf]);
            oacc[nf] = mfma16(ph, vl, oacc[nf]);
            oacc[nf] = mfma16(pl, vh, oacc[nf]);
        }
        __builtin_amdgcn_s_setprio(0);
    }

    // epilogue: divide by l, write bf16 hi/lo attnO directly (fused conversion)
#pragma unroll
    for (int r = 0; r < 4; r++) {
        float inv = 1.0f / l_r[r];
        int srow = qt * QB + wid * 16 + l4 * 4 + r;
        size_t ob = ((size_t)b * S_LEN + srow) * DMODEL + h * HD;
#pragma unroll
        for (int nf = 0; nf < 8; nf++) {
            unsigned short hh, ll;
            splitf(oacc[nf][r] * inv, hh, ll);
            AOh[ob + nf * 16 + l15] = hh;
            AOl[ob + nf * 16 + l15] = ll;
        }
    }
}

// ---------------------------------------------------------------------------
extern "C" void kernel_launch(void* const* d_in, const int* in_sizes, int n_in,
                              void* d_out, int out_size, void* d_ws, size_t ws_size,
                              hipStream_t stream)
{
    const float* x  = (const float*)d_in[0];
    const float* Wq = (const float*)d_in[1];
    const float* bq = (const float*)d_in[2];
    const float* Wk = (const float*)d_in[3];
    const float* bk = (const float*)d_in[4];
    const float* Wv = (const float*)d_in[5];
    const float* bv = (const float*)d_in[6];
    const float* Wo = (const float*)d_in[7];
    const float* bo = (const float*)d_in[8];
    float* out = (float*)d_out;

    char* ws = (char*)d_ws;
    const size_t SZ = 12582912;                 // 6.29M elems * 2B

    float* cosT = (float*)ws;           ws += 524288;
    float* sinT = (float*)ws;           ws += 524288;
    unsigned short* Xh  = (unsigned short*)ws; ws += SZ;   // alias: AOh
    unsigned short* Xl  = (unsigned short*)ws; ws += SZ;   // alias: AOl
    unsigned short* Wch = (unsigned short*)ws; ws += 14155776;  // 4608x1536; alias: Woh
    unsigned short* Wcl = (unsigned short*)ws; ws += 14155776;  // alias: Wol
    unsigned short* Qhp = (unsigned short*)ws; ws += SZ;
    unsigned short* Qlp = (unsigned short*)ws; ws += SZ;
    unsigned short* Khp = (unsigned short*)ws; ws += SZ;
    unsigned short* Klp = (unsigned short*)ws; ws += SZ;
    unsigned short* Vhp = (unsigned short*)ws; ws += SZ;
    unsigned short* Vlp = (unsigned short*)ws; ws += SZ;
    unsigned short* VTh = (unsigned short*)ws; ws += SZ;
    unsigned short* VTl = (unsigned short*)ws; ws += SZ;

    unsigned short* AOh = Xh;                   // X dead after QKV GEMM
    unsigned short* AOl = Xl;
    unsigned short* Woh = Wch;                  // Wqkv dead after QKV GEMM
    unsigned short* Wol = Wcl;

    const int M = NBATCH * S_LEN;               // 4096
    const int NW = 1536 * 1536;                 // one weight matrix

    rope_table_kernel<<<dim3(S_LEN), dim3(64), 0, stream>>>(cosT, sinT);

    // convert x and the three QKV weights (concatenated along N)
    conv_hl_kernel<<<dim3(M * DMODEL / 8 / 256), 256, 0, stream>>>(x, Xh, Xl, M * DMODEL / 8);
    conv_hl_kernel<<<dim3(NW / 8 / 256), 256, 0, stream>>>(Wq, Wch, Wcl, NW / 8);
    conv_hl_kernel<<<dim3(NW / 8 / 256), 256, 0, stream>>>(Wk, Wch + (size_t)NW, Wcl + (size_t)NW, NW / 8);
    conv_hl_kernel<<<dim3(NW / 8 / 256), 256, 0, stream>>>(Wv, Wch + (size_t)2 * NW, Wcl + (size_t)2 * NW, NW / 8);

    // fused QKV projection: M=4096, N=4608, K=1536
    gemm_hl_kernel<<<dim3(M / BM, 4608 / BN), 256, 0, stream>>>(
        Xh, Xl, Wch, Wcl, M, 4608, DMODEL,
        nullptr, nullptr, Qhp, Qlp, Khp, Klp, Vhp, Vlp,
        bq, bk, bv, cosT, sinT, 1);

    transpose_vt_kernel<<<dim3(S_LEN / 64, HD / 64, NBATCH * NHEADS), 256, 0, stream>>>(
        Vhp, Vlp, VTh, VTl);

    conv_hl_kernel<<<dim3(NW / 8 / 256), 256, 0, stream>>>(Wo, Woh, Wol, NW / 8);

    // flash writes attnO directly as bf16 hi/lo (conversion fused in epilogue)
    flash_kernel<<<dim3(S_LEN / QB, NBATCH * NHEADS), 256, 0, stream>>>(
        Qhp, Qlp, Khp, Klp, VTh, VTl, AOh, AOl);

    // output projection
    gemm_hl_kernel<<<dim3(M / BM, DMODEL / BN), 256, 0, stream>>>(
        AOh, AOl, Woh, Wol, M, DMODEL, DMODEL,
        out, bo, nullptr, nullptr, nullptr, nullptr, nullptr, nullptr,
        nullptr, nullptr, nullptr, nullptr, nullptr, 0);
}

// Round 8
// 599.807 us; speedup vs baseline: 1.4838x; 1.1305x over previous
//
#include <hip/hip_runtime.h>
#include <math.h>

#define S_LEN   2048
#define NHEADS  12
#define HD      128
#define DMODEL  1536
#define NBATCH  2

typedef __bf16 bf16x8 __attribute__((ext_vector_type(8)));
typedef float  f32x4  __attribute__((ext_vector_type(4)));
typedef unsigned short u16x8 __attribute__((ext_vector_type(8)));

// ALiBi slopes for n=12 heads: pow2_slopes(8) + pow2_slopes(16)[0::2][:4]
__constant__ float c_slopes[NHEADS] = {
    0.5f, 0.25f, 0.125f, 0.0625f, 0.03125f, 0.015625f, 0.0078125f, 0.00390625f,
    0.70710678118654752f, 0.35355339059327379f,
    0.17677669529663689f, 0.08838834764831845f
};

__device__ __forceinline__ unsigned short f2bf(float x) {
    unsigned int u = __float_as_uint(x);
    u += 0x7FFFu + ((u >> 16) & 1u);   // RNE (no NaN inputs here)
    return (unsigned short)(u >> 16);
}
__device__ __forceinline__ float bf2f(unsigned short h) {
    return __uint_as_float(((unsigned int)h) << 16);
}
__device__ __forceinline__ void splitf(float v, unsigned short &h, unsigned short &l) {
    h = f2bf(v);
    l = f2bf(v - bf2f(h));
}
__device__ __forceinline__ f32x4 mfma16(bf16x8 a, bf16x8 b, f32x4 c) {
    return __builtin_amdgcn_mfma_f32_16x16x32_bf16(a, b, c, 0, 0, 0);
}
// async global->LDS, 16B per lane; LDS dest = wave-uniform base + lane*16
__device__ __forceinline__ void gl_lds16(const void* g, void* l) {
    __builtin_amdgcn_global_load_lds(
        (const __attribute__((address_space(1))) unsigned int*)g,
        (__attribute__((address_space(3))) unsigned int*)l, 16, 0, 0);
}

// ---------------------------------------------------------------------------
// RoPE tables [S][64] fp32 (matches jnp fp32 pipeline)
// ---------------------------------------------------------------------------
__global__ void rope_table_kernel(float* __restrict__ cosT, float* __restrict__ sinT) {
    const int s = blockIdx.x;
    const int i = threadIdx.x;                       // 0..63
    double inv = exp(-((double)i / 64.0) * 9.210340371976184);  // 10000^(-i/64)
    float argf = (float)s * (float)inv;
    double a = (double)argf;
    cosT[s * 64 + i] = (float)cos(a);
    sinT[s * 64 + i] = (float)sin(a);
}

// ---------------------------------------------------------------------------
// Elementwise fp32 -> bf16 hi/lo split (8 elems/thread, vectorized)
// ---------------------------------------------------------------------------
__global__ __launch_bounds__(256)
void conv_hl_kernel(const float* __restrict__ src,
                    unsigned short* __restrict__ dh,
                    unsigned short* __restrict__ dl, int n8)
{
    int idx = blockIdx.x * 256 + threadIdx.x;
    if (idx >= n8) return;
    const float4* s = (const float4*)src + (size_t)idx * 2;
    float4 a = s[0], b = s[1];
    u16x8 hv, lv;
    unsigned short th, tl;
    splitf(a.x, th, tl); hv[0] = th; lv[0] = tl;
    splitf(a.y, th, tl); hv[1] = th; lv[1] = tl;
    splitf(a.z, th, tl); hv[2] = th; lv[2] = tl;
    splitf(a.w, th, tl); hv[3] = th; lv[3] = tl;
    splitf(b.x, th, tl); hv[4] = th; lv[4] = tl;
    splitf(b.y, th, tl); hv[5] = th; lv[5] = tl;
    splitf(b.z, th, tl); hv[6] = th; lv[6] = tl;
    splitf(b.w, th, tl); hv[7] = th; lv[7] = tl;
    *(u16x8*)(dh + (size_t)idx * 8) = hv;
    *(u16x8*)(dl + (size_t)idx * 8) = lv;
}

// ---------------------------------------------------------------------------
// Tiled transpose: (BH, S, HD) -> (BH, HD, S) for hi and lo arrays.
// ---------------------------------------------------------------------------
__global__ __launch_bounds__(256, 4)
void transpose_vt_kernel(const unsigned short* __restrict__ inH,
                         const unsigned short* __restrict__ inL,
                         unsigned short* __restrict__ outH,
                         unsigned short* __restrict__ outL)
{
    __shared__ __align__(16) unsigned short Th[64 * 65], Tl[64 * 65];
    const int tid = threadIdx.x;
    const int sx = blockIdx.x * 64, dx = blockIdx.y * 64;
    const int bh = blockIdx.z;
    const size_t ibase = (size_t)bh * S_LEN * HD;
    const size_t obase = (size_t)bh * HD * S_LEN;

#pragma unroll
    for (int t = 0; t < 2; t++) {
        int srow = (tid >> 3) + 32 * t;
        int c8 = tid & 7;
        u16x8 vh = *(const u16x8*)(inH + ibase + (size_t)(sx + srow) * HD + dx + c8 * 8);
        u16x8 vl = *(const u16x8*)(inL + ibase + (size_t)(sx + srow) * HD + dx + c8 * 8);
#pragma unroll
        for (int j = 0; j < 8; j++) {
            Th[(c8 * 8 + j) * 65 + srow] = vh[j];
            Tl[(c8 * 8 + j) * 65 + srow] = vl[j];
        }
    }
    __syncthreads();
#pragma unroll
    for (int t = 0; t < 2; t++) {
        int drow = (tid >> 3) + 32 * t;
        int c8 = tid & 7;
        u16x8 vh, vl;
#pragma unroll
        for (int j = 0; j < 8; j++) {
            vh[j] = Th[drow * 65 + c8 * 8 + j];
            vl[j] = Tl[drow * 65 + c8 * 8 + j];
        }
        *(u16x8*)(outH + obase + (size_t)(dx + drow) * S_LEN + sx + c8 * 8) = vh;
        *(u16x8*)(outL + obase + (size_t)(dx + drow) * S_LEN + sx + c8 * 8) = vl;
    }
}

// ---------------------------------------------------------------------------
// Split-bf16 GEMM, global_load_lds staging + 2-way XOR swizzle.
// LDS per array: linear [128 rows][64B], slot16 permuted by (row>>1)&3.
// Staging source address carries the inverse permutation (both-sides rule).
// ---------------------------------------------------------------------------
#define BM 128
#define BN 128
#define BK 32

__global__ __launch_bounds__(256, 3)
void gemm_hl_kernel(const unsigned short* __restrict__ Agh, const unsigned short* __restrict__ Agl,
                    const unsigned short* __restrict__ Bgh, const unsigned short* __restrict__ Bgl,
                    int M, int N, int K,
                    float* __restrict__ outF, const float* __restrict__ bO,
                    unsigned short* __restrict__ Qh, unsigned short* __restrict__ Ql,
                    unsigned short* __restrict__ Kh, unsigned short* __restrict__ Kl,
                    unsigned short* __restrict__ Vh, unsigned short* __restrict__ Vl,
                    const float* __restrict__ bq, const float* __restrict__ bk,
                    const float* __restrict__ bv,
                    const float* __restrict__ cosT, const float* __restrict__ sinT,
                    int mode)
{
    __shared__ __align__(16) unsigned short Ah[BM * BK], Al[BM * BK];  // 8 KB each
    __shared__ __align__(16) unsigned short Bh[BN * BK], Bl[BN * BK];

    const int tid  = threadIdx.x;
    const int lane = tid & 63;
    const int w    = tid >> 6;
    const int wm   = w >> 1, wn = w & 1;
    const int m0   = blockIdx.x * BM, n0 = blockIdx.y * BN;
    const int l15  = lane & 15, l4 = lane >> 4;
    // fragment-read swizzle byte offset within a 64B row (per-lane constant)
    const int swb  = ((l4 ^ ((l15 >> 1) & 3)) << 4);

    f32x4 acc[4][4] = {};

    const int KT = K / BK;
    for (int kt = 0; kt < KT; ++kt) {
        __syncthreads();   // all waves done reading LDS from previous step
        // stage 4 arrays x 8KB via global_load_lds; 2 wave-instrs per array
#pragma unroll
        for (int j = 0; j < 2; j++) {
            int row  = w * 32 + j * 16 + (lane >> 2);
            int slot = lane & 3;
            int sw   = ((slot ^ ((row >> 1) & 3)) << 4);
            size_t ao = ((size_t)(m0 + row) * K + (size_t)kt * BK) * 2 + sw;
            size_t bo2 = ((size_t)(n0 + row) * K + (size_t)kt * BK) * 2 + sw;
            int ldsb = w * 2048 + j * 1024;
            gl_lds16((const char*)Agh + ao,  (char*)Ah + ldsb);
            gl_lds16((const char*)Agl + ao,  (char*)Al + ldsb);
            gl_lds16((const char*)Bgh + bo2, (char*)Bh + ldsb);
            gl_lds16((const char*)Bgl + bo2, (char*)Bl + ldsb);
        }
        __syncthreads();   // compiler drains vmcnt(0) before barrier -> data ready

        bf16x8 ah[4], al[4], bh[4], bl[4];
#pragma unroll
        for (int mi = 0; mi < 4; mi++) {
            int r = wm * 64 + mi * 16 + l15;
            ah[mi] = *(const bf16x8*)((const char*)Ah + r * 64 + swb);
            al[mi] = *(const bf16x8*)((const char*)Al + r * 64 + swb);
        }
#pragma unroll
        for (int ni = 0; ni < 4; ni++) {
            int r = wn * 64 + ni * 16 + l15;
            bh[ni] = *(const bf16x8*)((const char*)Bh + r * 64 + swb);
            bl[ni] = *(const bf16x8*)((const char*)Bl + r * 64 + swb);
        }
        __builtin_amdgcn_s_setprio(1);
#pragma unroll
        for (int mi = 0; mi < 4; mi++) {
#pragma unroll
            for (int ni = 0; ni < 4; ni++) {
                acc[mi][ni] = mfma16(ah[mi], bh[ni], acc[mi][ni]);
                acc[mi][ni] = mfma16(ah[mi], bl[ni], acc[mi][ni]);
                acc[mi][ni] = mfma16(al[mi], bh[ni], acc[mi][ni]);
            }
        }
        __builtin_amdgcn_s_setprio(0);
    }

    // epilogue
#pragma unroll
    for (int ni = 0; ni < 4; ni++) {
        int col = n0 + wn * 64 + ni * 16 + l15;
        float bvv;
        unsigned short *dh = nullptr, *dl = nullptr;
        int colL = col, dorope = 0;
        if (mode == 0) {
            bvv = bO[col];
        } else {
            int which = col / 1536;            // block-uniform (BN | 1536)
            colL = col - which * 1536;
            const float* bias = (which == 0) ? bq : (which == 1) ? bk : bv;
            dh = (which == 0) ? Qh : (which == 1) ? Kh : Vh;
            dl = (which == 0) ? Ql : (which == 1) ? Kl : Vl;
            dorope = (which < 2);
            bvv = bias[colL];
        }
        int hcol = colL >> 7;            // head
        int d    = colL & (HD - 1);      // dim within head
#pragma unroll
        for (int mi = 0; mi < 4; mi++) {
#pragma unroll
            for (int r = 0; r < 4; r++) {
                int row = m0 + wm * 64 + mi * 16 + l4 * 4 + r;
                float v = acc[mi][ni][r] + bvv;
                if (mode == 0) {
                    outF[(size_t)row * N + col] = v;
                } else {
                    int bb = row >> 11;
                    int ss = row & (S_LEN - 1);
                    if (dorope) {
                        float p  = __shfl_xor(v, 1);
                        float cc = cosT[ss * 64 + (d >> 1)];
                        float sn = sinT[ss * 64 + (d >> 1)];
                        v = (d & 1) ? fmaf(p, sn, v * cc) : fmaf(-p, sn, v * cc);
                    }
                    unsigned short hh, ll;
                    splitf(v, hh, ll);
                    size_t o = ((size_t)(bb * NHEADS + hcol) * S_LEN + ss) * HD + d;
                    dh[o] = hh;
                    dl[o] = ll;
                }
            }
        }
    }
}

// ---------------------------------------------------------------------------
// Flash attention, ALiBi (non-causal), split-bf16 MFMA.
// 4 waves x 16 q-rows; KB=32; descending k + vote-gated exact skip-rescale.
// K/V staging via global_load_lds into linear LDS with XOR swizzles:
//   K tiles [32][256B]: chunk16 ^= row&7  (2-way)
//   V^T tiles [128][64B]: slot ^= (row>>1)&3  (2-way)
// ---------------------------------------------------------------------------
#define QB  64
#define KB  32
#define LPD 40    // P LDS stride (32 + 8 pad)

__global__ __launch_bounds__(256, 3)
void flash_kernel(const unsigned short* __restrict__ Qh, const unsigned short* __restrict__ Ql,
                  const unsigned short* __restrict__ Kh, const unsigned short* __restrict__ Kl,
                  const unsigned short* __restrict__ VTh, const unsigned short* __restrict__ VTl,
                  unsigned short* __restrict__ AOh, unsigned short* __restrict__ AOl)
{
    __shared__ __align__(16) unsigned short Ksh[KB * HD], Ksl[KB * HD];  // 8 KB each
    __shared__ __align__(16) unsigned short Vth[HD * KB], Vtl[HD * KB];  // 8 KB each
    __shared__ __align__(16) unsigned short Psh[4 * 16 * LPD], Psl[4 * 16 * LPD];

    const int tid  = threadIdx.x, lane = tid & 63, w = tid >> 6;  // w 0..3
    const int l15  = lane & 15, l4 = lane >> 4;
    const int kq   = l4 * 8;
    const int qt   = blockIdx.x, bh = blockIdx.y;
    const int b    = bh / NHEADS, h = bh % NHEADS;
    const float slope = c_slopes[h];
    const float scale = 0.088388347648318447f;   // 1/sqrt(128)
    const int swb  = ((l4 ^ ((l15 >> 1) & 3)) << 4);   // V-read swizzle
    const int swk  = ((l15 & 7) << 4);                  // K-read swizzle

    const size_t base  = (size_t)bh * S_LEN * HD;
    const size_t vbase = (size_t)bh * HD * S_LEN;

    // Q fragments in registers (A-operand layout: m=l15, k-chunk by l4)
    bf16x8 qfh[4], qfl[4];
    {
        const int qrow = qt * QB + w * 16 + l15;
#pragma unroll
        for (int ks = 0; ks < 4; ks++) {
            size_t o = base + (size_t)qrow * HD + ks * 32 + kq;
            qfh[ks] = *(const bf16x8*)(Qh + o);
            qfl[ks] = *(const bf16x8*)(Ql + o);
        }
    }

    float m_r[4], l_r[4];
#pragma unroll
    for (int r = 0; r < 4; r++) { m_r[r] = -1e30f; l_r[r] = 0.0f; }
    f32x4 oacc[8] = {};

    unsigned short* Pmh = &Psh[w * 16 * LPD];
    unsigned short* Pml = &Psl[w * 16 * LPD];

    for (int it = 0; it < S_LEN / KB; ++it) {
        const int kt = (S_LEN / KB - 1) - it;   // descending k (ALiBi max first)
        __syncthreads();
        // stage K [32 rows x 256B] and V^T [128 rows x 64B], 8 gl_lds per wave
#pragma unroll
        for (int j = 0; j < 2; j++) {
            {   // K arrays
                int row  = w * 8 + j * 4 + (lane >> 4);
                int innp = ((lane & 15) << 4) ^ ((row & 7) << 4);
                size_t ko = (base + (size_t)(kt * KB + row) * HD) * 2 + innp;
                int ldsb = w * 2048 + j * 1024;
                gl_lds16((const char*)Kh + ko, (char*)Ksh + ldsb);
                gl_lds16((const char*)Kl + ko, (char*)Ksl + ldsb);
            }
            {   // V^T arrays
                int row = w * 32 + j * 16 + (lane >> 2);
                int sw  = (((lane & 3) ^ ((row >> 1) & 3)) << 4);
                size_t vo = (vbase + (size_t)row * S_LEN + (size_t)kt * KB) * 2 + sw;
                int ldsb = w * 2048 + j * 1024;
                gl_lds16((const char*)VTh + vo, (char*)Vth + ldsb);
                gl_lds16((const char*)VTl + vo, (char*)Vtl + ldsb);
            }
        }
        __syncthreads();   // vmcnt(0) drained by compiler before barrier

        // QK^T: D[q16 x key32] over hd=128
        f32x4 sc[2] = {};
        __builtin_amdgcn_s_setprio(1);
#pragma unroll
        for (int ks = 0; ks < 4; ks++) {
#pragma unroll
            for (int nf = 0; nf < 2; nf++) {
                int krow = nf * 16 + l15;
                int kbyte = krow * 256 + ((ks * 64 + l4 * 16) ^ swk);
                bf16x8 kh = *(const bf16x8*)((const char*)Ksh + kbyte);
                bf16x8 kl = *(const bf16x8*)((const char*)Ksl + kbyte);
                sc[nf] = mfma16(qfh[ks], kh, sc[nf]);
                sc[nf] = mfma16(qfh[ks], kl, sc[nf]);
                sc[nf] = mfma16(qfl[ks], kh, sc[nf]);
            }
        }
        __builtin_amdgcn_s_setprio(0);

        // online softmax, exact skip-rescale (descending k: max locks in early)
        float mnew[4];
        int grow = 0;
        const float bias0 = slope * (float)(kt * KB + l15);
        const float bias1 = slope * (float)(kt * KB + 16 + l15);
#pragma unroll
        for (int r = 0; r < 4; r++) {
            float s0 = fmaf(sc[0][r], scale, bias0);
            float s1 = fmaf(sc[1][r], scale, bias1);
            sc[0][r] = s0;
            sc[1][r] = s1;
            float mx = fmaxf(s0, s1);
            mx = fmaxf(mx, __shfl_xor(mx, 1));
            mx = fmaxf(mx, __shfl_xor(mx, 2));
            mx = fmaxf(mx, __shfl_xor(mx, 4));
            mx = fmaxf(mx, __shfl_xor(mx, 8));
            mnew[r] = fmaxf(m_r[r], mx);
            grow |= (mnew[r] > m_r[r]) ? 1 : 0;
        }
        if (__any(grow)) {
#pragma unroll
            for (int r = 0; r < 4; r++) {
                float corr = __expf(m_r[r] - mnew[r]);
                m_r[r] = mnew[r];
                l_r[r] *= corr;
#pragma unroll
                for (int nf = 0; nf < 8; nf++) oacc[nf][r] *= corr;
            }
        }
#pragma unroll
        for (int r = 0; r < 4; r++) {
            float p0 = __expf(sc[0][r] - m_r[r]);
            float p1 = __expf(sc[1][r] - m_r[r]);
            sc[0][r] = p0;
            sc[1][r] = p1;
            float rs = p0 + p1;
            rs += __shfl_xor(rs, 1);
            rs += __shfl_xor(rs, 2);
            rs += __shfl_xor(rs, 4);
            rs += __shfl_xor(rs, 8);
            l_r[r] += rs;
        }

        // P -> LDS (hi/lo), C-layout -> A-operand layout
#pragma unroll
        for (int nf = 0; nf < 2; nf++) {
#pragma unroll
            for (int r = 0; r < 4; r++) {
                unsigned short hh, ll;
                splitf(sc[nf][r], hh, ll);
                int row = l4 * 4 + r, col = nf * 16 + l15;
                Pmh[row * LPD + col] = hh;
                Pml[row * LPD + col] = ll;
            }
        }
        asm volatile("s_waitcnt lgkmcnt(0)" ::: "memory");
        __builtin_amdgcn_sched_barrier(0);

        // PV: O[q16 x hd128] += P[q16 x key32] @ V[key32 x hd]
        bf16x8 ph = *(const bf16x8*)&Pmh[l15 * LPD + kq];
        bf16x8 pl = *(const bf16x8*)&Pml[l15 * LPD + kq];
        __builtin_amdgcn_s_setprio(1);
#pragma unroll
        for (int nf = 0; nf < 8; nf++) {
            int vrow = nf * 16 + l15;
            bf16x8 vh = *(const bf16x8*)((const char*)Vth + vrow * 64 + swb);
            bf16x8 vl = *(const bf16x8*)((const char*)Vtl + vrow * 64 + swb);
            oacc[nf] = mfma16(ph, vh, oacc[nf]);
            oacc[nf] = mfma16(ph, vl, oacc[nf]);
            oacc[nf] = mfma16(pl, vh, oacc[nf]);
        }
        __builtin_amdgcn_s_setprio(0);
    }

    // epilogue: divide by l, write bf16 hi/lo attnO directly (fused conversion)
#pragma unroll
    for (int r = 0; r < 4; r++) {
        float inv = 1.0f / l_r[r];
        int srow = qt * QB + w * 16 + l4 * 4 + r;
        size_t ob = ((size_t)b * S_LEN + srow) * DMODEL + h * HD;
#pragma unroll
        for (int nf = 0; nf < 8; nf++) {
            unsigned short hh, ll;
            splitf(oacc[nf][r] * inv, hh, ll);
            AOh[ob + nf * 16 + l15] = hh;
            AOl[ob + nf * 16 + l15] = ll;
        }
    }
}

// ---------------------------------------------------------------------------
extern "C" void kernel_launch(void* const* d_in, const int* in_sizes, int n_in,
                              void* d_out, int out_size, void* d_ws, size_t ws_size,
                              hipStream_t stream)
{
    const float* x  = (const float*)d_in[0];
    const float* Wq = (const float*)d_in[1];
    const float* bq = (const float*)d_in[2];
    const float* Wk = (const float*)d_in[3];
    const float* bk = (const float*)d_in[4];
    const float* Wv = (const float*)d_in[5];
    const float* bv = (const float*)d_in[6];
    const float* Wo = (const float*)d_in[7];
    const float* bo = (const float*)d_in[8];
    float* out = (float*)d_out;

    char* ws = (char*)d_ws;
    const size_t SZ = 12582912;                 // 6.29M elems * 2B

    float* cosT = (float*)ws;           ws += 524288;
    float* sinT = (float*)ws;           ws += 524288;
    unsigned short* Xh  = (unsigned short*)ws; ws += SZ;   // alias: AOh
    unsigned short* Xl  = (unsigned short*)ws; ws += SZ;   // alias: AOl
    unsigned short* Wch = (unsigned short*)ws; ws += 14155776;  // 4608x1536; alias: Woh
    unsigned short* Wcl = (unsigned short*)ws; ws += 14155776;  // alias: Wol
    unsigned short* Qhp = (unsigned short*)ws; ws += SZ;
    unsigned short* Qlp = (unsigned short*)ws; ws += SZ;
    unsigned short* Khp = (unsigned short*)ws; ws += SZ;
    unsigned short* Klp = (unsigned short*)ws; ws += SZ;
    unsigned short* Vhp = (unsigned short*)ws; ws += SZ;
    unsigned short* Vlp = (unsigned short*)ws; ws += SZ;
    unsigned short* VTh = (unsigned short*)ws; ws += SZ;
    unsigned short* VTl = (unsigned short*)ws; ws += SZ;

    unsigned short* AOh = Xh;                   // X dead after QKV GEMM
    unsigned short* AOl = Xl;
    unsigned short* Woh = Wch;                  // Wqkv dead after QKV GEMM
    unsigned short* Wol = Wcl;

    const int M = NBATCH * S_LEN;               // 4096
    const int NW = 1536 * 1536;                 // one weight matrix

    rope_table_kernel<<<dim3(S_LEN), dim3(64), 0, stream>>>(cosT, sinT);

    // convert x and the three QKV weights (concatenated along N)
    conv_hl_kernel<<<dim3(M * DMODEL / 8 / 256), 256, 0, stream>>>(x, Xh, Xl, M * DMODEL / 8);
    conv_hl_kernel<<<dim3(NW / 8 / 256), 256, 0, stream>>>(Wq, Wch, Wcl, NW / 8);
    conv_hl_kernel<<<dim3(NW / 8 / 256), 256, 0, stream>>>(Wk, Wch + (size_t)NW, Wcl + (size_t)NW, NW / 8);
    conv_hl_kernel<<<dim3(NW / 8 / 256), 256, 0, stream>>>(Wv, Wch + (size_t)2 * NW, Wcl + (size_t)2 * NW, NW / 8);

    // fused QKV projection: M=4096, N=4608, K=1536
    gemm_hl_kernel<<<dim3(M / BM, 4608 / BN), 256, 0, stream>>>(
        Xh, Xl, Wch, Wcl, M, 4608, DMODEL,
        nullptr, nullptr, Qhp, Qlp, Khp, Klp, Vhp, Vlp,
        bq, bk, bv, cosT, sinT, 1);

    transpose_vt_kernel<<<dim3(S_LEN / 64, HD / 64, NBATCH * NHEADS), 256, 0, stream>>>(
        Vhp, Vlp, VTh, VTl);

    conv_hl_kernel<<<dim3(NW / 8 / 256), 256, 0, stream>>>(Wo, Woh, Wol, NW / 8);

    // flash writes attnO directly as bf16 hi/lo (conversion fused in epilogue)
    flash_kernel<<<dim3(S_LEN / QB, NBATCH * NHEADS), 256, 0, stream>>>(
        Qhp, Qlp, Khp, Klp, VTh, VTl, AOh, AOl);

    // output projection
    gemm_hl_kernel<<<dim3(M / BM, DMODEL / BN), 256, 0, stream>>>(
        AOh, AOl, Woh, Wol, M, DMODEL, DMODEL,
        out, bo, nullptr, nullptr, nullptr, nullptr, nullptr, nullptr,
        nullptr, nullptr, nullptr, nullptr, nullptr, 0);
}